// Round 13
// baseline (40.063 us; speedup 1.0000x reference)
//
#include <hip/hip_runtime.h>
#include <cmath>

typedef unsigned short u16;
typedef __bf16 bf16x8 __attribute__((ext_vector_type(8)));
typedef float f32x4 __attribute__((ext_vector_type(4)));
typedef unsigned short u16x4 __attribute__((ext_vector_type(4)));

#define BATCH 16384
#define NTREE 32
#define NINT 63
#define NLEAF 64
#define FDIM 256
#define MT 128     // batch rows per block
#define TPB 2      // trees per block
#define BK 32      // K per staging step
#define KSTEPS 8   // 256/32

typedef __attribute__((address_space(3))) void lvoid;
typedef __attribute__((address_space(1))) const void gvoid;
__device__ __forceinline__ void gload16(const void* g, void* l) {
    // DMA 16B/lane global->LDS; LDS dest = wave-uniform base + lane*16 (HW rule)
    __builtin_amdgcn_global_load_lds((gvoid*)g, (lvoid*)l, 16, 0, 0);
}

__device__ __forceinline__ u16 f2bf(float f) {
    unsigned int x = __float_as_uint(f);
    x += 0x7fffu + ((x >> 16) & 1u);   // round-to-nearest-even
    return (u16)(x >> 16);
}

// D-row slot s (0..63) -> heap node id (R6-verified permutation).
__device__ __forceinline__ int slot2node(int slot) {
    int lg = (slot >> 2) & 3;
    int v = ((slot >> 4) << 2) | (slot & 3);
    if (v == 0)  return (lg & 1) ? (1 + (lg >> 1)) : 0;
    if (v == 1)  return 3 + lg;
    if (v < 4)   return 7 + 2 * lg + (v - 2);
    if (v < 8)   return 15 + 4 * lg + (v - 4);
    return 31 + 8 * lg + (v - 8);
}

__global__ void convert_kernel(const float* __restrict__ x, const float* __restrict__ W,
                               const float* __restrict__ b,
                               u16* __restrict__ xb, u16* __restrict__ Wb,
                               float* __restrict__ bperm) {
    int idx = blockIdx.x * blockDim.x + threadIdx.x;
    int stride = gridDim.x * blockDim.x;
    const int NXQ = BATCH * FDIM / 4;
    for (int i = idx; i < NXQ; i += stride) {
        float4 v = ((const float4*)x)[i];
        u16x4 o = { f2bf(v.x), f2bf(v.y), f2bf(v.z), f2bf(v.w) };
        ((u16x4*)xb)[i] = o;
    }
    // Wb: [tree][64 slots (permuted nodes, root duplicated)][256 features]
    const int NWQ = NTREE * NLEAF * FDIM / 4;
    for (int i = idx; i < NWQ; i += stride) {
        int t = i / (NLEAF * FDIM / 4);
        int r = i % (NLEAF * FDIM / 4);
        int slot = r / (FDIM / 4);
        int kq = r % (FDIM / 4);
        int node = slot2node(slot);
        float4 v = ((const float4*)(W + ((size_t)t * NINT + node) * FDIM))[kq];
        u16x4 o = { f2bf(v.x), f2bf(v.y), f2bf(v.z), f2bf(v.w) };
        ((u16x4*)Wb)[i] = o;
    }
    if (idx < NTREE * NLEAF)
        bperm[idx] = b[(idx >> 6) * NINT + slot2node(idx & 63)];
}

// R12 geometry (4 waves, 128 rows x 2 trees, swapped GEMM, BK=32) with a REAL
// T3/T4 pipeline: 3-buffer rotation, depth-2 DMA prefetch, counted
// s_waitcnt vmcnt(4) + RAW s_barrier (no compiler vmcnt(0) drain — m201
// template precedent). Steady state: wait vmcnt(4) [stage(st) landed,
// stage(st+1) in flight] -> s_barrier -> issue stage(st+2) into buf[(st+2)%3]
// (last read at step st-1; safe) -> ds_read+MFMA on buf[st%3].
// Swizzle cc^( (row>>1)&3 ) both sides (R12-verified). Bias-folded acc init.
// Epilogue: R6-verified register-only tree eval. LDS 48KB -> 3 blocks/CU.
__global__ __launch_bounds__(256, 4) void softgbm_main(
    const u16* __restrict__ xb, const u16* __restrict__ Wb,
    const float* __restrict__ bperm, const float* __restrict__ phig,
    float* __restrict__ partial) {
    __shared__ u16 Ash[3][MT * BK];   // 3 x 8KB
    __shared__ u16 Bsh[3][MT * BK];   // 3 x 8KB

    const int tid = threadIdx.x;
    const int lane = tid & 63, wv = tid >> 6;
    const int t0 = blockIdx.y * TPB;
    const int m0 = blockIdx.x * MT;
    const int tp = wv & 1, rg = wv >> 1;
    const int frow = lane & 15, lg = lane >> 4;
    const int t = t0 + tp;

    // ---- staging: 512 chunks per tile -> 2 chunks/thread; swizzled source
    const u16* agp[2]; const u16* bgp[2]; int ldst[2];
    #pragma unroll
    for (int j = 0; j < 2; ++j) {
        int cl = j * 256 + tid;
        int row = cl >> 2, p = cl & 3;
        int cc = p ^ ((row >> 1) & 3);              // involution per row
        agp[j] = Wb + (size_t)(t0 * NLEAF + row) * FDIM + cc * 8;
        bgp[j] = xb + (size_t)(m0 + row) * FDIM + cc * 8;
        ldst[j] = cl * 8;
    }

    // ---- frag read byte-offsets (same XOR on read side)
    int aoffs[4], boffs[4];
    #pragma unroll
    for (int ar = 0; ar < 4; ++ar) {
        int r = tp * 64 + ar * 16 + frow;
        aoffs[ar] = r * 64 + ((lg ^ ((r >> 1) & 3)) * 16);
    }
    #pragma unroll
    for (int bc = 0; bc < 4; ++bc) {
        int n = rg * 64 + bc * 16 + frow;
        boffs[bc] = n * 64 + ((lg ^ ((n >> 1) & 3)) * 16);
    }

    // ---- tables FIRST (so their VMEM ops precede staging in the vmcnt order)
    float pha[8], phd[8];
    #pragma unroll
    for (int i = 0; i < 8; ++i) {
        float2 p2 = *(const float2*)&phig[(size_t)t * NLEAF + lg * 16 + 2 * i];
        pha[i] = p2.x; phd[i] = p2.y - p2.x;
    }
    f32x4 acc[4][4];
    #pragma unroll
    for (int ar = 0; ar < 4; ++ar)
        #pragma unroll
        for (int j = 0; j < 4; ++j) {
            float bv = bperm[t * 64 + ar * 16 + lg * 4 + j];
            #pragma unroll
            for (int bc = 0; bc < 4; ++bc) acc[ar][bc][j] = bv;
        }

    // ---- prologue: stage(0)->buf0, stage(1)->buf1 (8 loads in flight)
    #pragma unroll
    for (int j = 0; j < 2; ++j) {
        gload16(agp[j], &Ash[0][ldst[j]]);
        gload16(bgp[j], &Bsh[0][ldst[j]]);
    }
    #pragma unroll
    for (int j = 0; j < 2; ++j) {
        gload16(agp[j] + BK, &Ash[1][ldst[j]]);
        gload16(bgp[j] + BK, &Bsh[1][ldst[j]]);
    }

    // ---- K loop: counted vmcnt + raw barrier; never a full drain mid-loop
    #pragma unroll
    for (int st = 0; st < KSTEPS; ++st) {
        if (st < KSTEPS - 1) asm volatile("s_waitcnt vmcnt(4)" ::: "memory");
        else                 asm volatile("s_waitcnt vmcnt(0)" ::: "memory");
        __builtin_amdgcn_s_barrier();
        if (st + 2 < KSTEPS) {
            #pragma unroll
            for (int j = 0; j < 2; ++j) {
                gload16(agp[j] + (st + 2) * BK, &Ash[(st + 2) % 3][ldst[j]]);
                gload16(bgp[j] + (st + 2) * BK, &Bsh[(st + 2) % 3][ldst[j]]);
            }
        }
        const char* Ab = (const char*)Ash[st % 3];
        const char* Bb = (const char*)Bsh[st % 3];
        bf16x8 af[4], bf_[4];
        #pragma unroll
        for (int ar = 0; ar < 4; ++ar) af[ar] = *(const bf16x8*)(Ab + aoffs[ar]);
        #pragma unroll
        for (int bc = 0; bc < 4; ++bc) bf_[bc] = *(const bf16x8*)(Bb + boffs[bc]);
        #pragma unroll
        for (int ar = 0; ar < 4; ++ar)
            #pragma unroll
            for (int bc = 0; bc < 4; ++bc)
                acc[ar][bc] = __builtin_amdgcn_mfma_f32_16x16x32_bf16(af[ar], bf_[bc], acc[ar][bc], 0, 0, 0);
    }

    // ---- in-register tree eval (R6-verified). Lane owns subtree lg.
    float tot[4];
    #pragma unroll
    for (int bc = 0; bc < 4; ++bc) {
        float pv[16];
        #pragma unroll
        for (int v2 = 0; v2 < 16; ++v2)
            pv[v2] = __builtin_amdgcn_rcpf(1.f + __expf(-acc[v2 >> 2][bc][v2 & 3]));
        float o = __shfl_xor(pv[0], 16);
        float proot = (lg & 1) ? o : pv[0];
        float pd1   = (lg & 1) ? pv[0] : o;
        float mb = ((lg >> 1) ? proot : 1.f - proot) * ((lg & 1) ? pd1 : 1.f - pd1);
        float m3[2], m4[4], m5[8];
        { float t1 = mb * pv[1]; m3[1] = t1; m3[0] = mb - t1; }
        #pragma unroll
        for (int i = 0; i < 2; ++i) { float t1 = m3[i] * pv[2 + i]; m4[2*i+1] = t1; m4[2*i] = m3[i] - t1; }
        #pragma unroll
        for (int i = 0; i < 4; ++i) { float t1 = m4[i] * pv[4 + i]; m5[2*i+1] = t1; m5[2*i] = m4[i] - t1; }
        float s = 0.f;
        #pragma unroll
        for (int i = 0; i < 8; ++i) s += m5[i] * (pha[i] + pv[8 + i] * phd[i]);
        s += __shfl_xor(s, 16);            // sum the 4 subtrees
        s += __shfl_xor(s, 32);
        tot[bc] = s;
    }
    // lane (lg,frow): row rg*64 + lg*16 + frow = rg*64 + lane, value tot[lg]
    float vout = (lg & 2) ? ((lg & 1) ? tot[3] : tot[2])
                          : ((lg & 1) ? tot[1] : tot[0]);
    partial[(size_t)t * BATCH + m0 + rg * 64 + lane] = vout;
}

__global__ void reduce_kernel(const float* __restrict__ partial, float* __restrict__ out) {
    int i = blockIdx.x * 256 + threadIdx.x;
    float s = 0.f;
    #pragma unroll
    for (int t = 0; t < NTREE; ++t) s += partial[(size_t)t * BATCH + i];
    out[i] = 0.1f * s;
}

extern "C" void kernel_launch(void* const* d_in, const int* in_sizes, int n_in,
                              void* d_out, int out_size, void* d_ws, size_t ws_size,
                              hipStream_t stream) {
    const float* x   = (const float*)d_in[0];
    const float* W   = (const float*)d_in[1];
    const float* b   = (const float*)d_in[2];
    const float* phi = (const float*)d_in[3];
    float* out = (float*)d_out;

    u16* xb = (u16*)d_ws;                                  // 16384*256 bf16 = 8 MB
    u16* Wb = xb + (size_t)BATCH * FDIM;                   // 32*64*256 bf16 = 1 MB
    float* partial = (float*)(Wb + (size_t)NTREE * NLEAF * FDIM);  // 32*16384 f32 = 2 MB
    float* bperm = partial + (size_t)NTREE * BATCH;        // 32*64 f32 = 8 KB

    convert_kernel<<<2048, 256, 0, stream>>>(x, W, b, xb, Wb, bperm);
    softgbm_main<<<dim3(BATCH / MT, NTREE / TPB), 256, 0, stream>>>(xb, Wb, bperm, phi, partial);
    reduce_kernel<<<BATCH / 256, 256, 0, stream>>>(partial, out);
}